// Round 1
// baseline (12612.421 us; speedup 1.0000x reference)
//
#include <hip/hip_runtime.h>
#include <hip/hip_bf16.h>
#include <math.h>

// Problem constants (match reference)
#define B_ROWS 8192
#define D_DIM  1024
#define C_COLS 4096
#define EPSN   1e-12f

// GEMM tiling
#define BM 128
#define BN 128
#define BK 32
#define CSPLIT 4
#define CPER (C_COLS / CSPLIT)  // 1024 centroids per block

// ---------------------------------------------------------------------------
// Kernel 1: inverse L2 norms. One block per row (emb rows first, then cen).
// inv = 1 / max(||x||, 1e-12)  -- matches F.normalize / reference.
// ---------------------------------------------------------------------------
__global__ __launch_bounds__(256) void norms_kernel(
    const float* __restrict__ emb, const float* __restrict__ cen,
    float* __restrict__ inv_emb, float* __restrict__ inv_cen)
{
    int row = blockIdx.x;
    const float* src; float* dst; int r;
    if (row < B_ROWS) { src = emb; r = row;          dst = inv_emb; }
    else              { src = cen; r = row - B_ROWS; dst = inv_cen; }

    // 256 threads x float4 = 1024 floats = one full row
    const float4 v = *(const float4*)(src + (size_t)r * D_DIM + threadIdx.x * 4);
    float ss = v.x * v.x + v.y * v.y + v.z * v.z + v.w * v.w;

    #pragma unroll
    for (int off = 32; off; off >>= 1) ss += __shfl_down(ss, off, 64);

    __shared__ float part[4];
    if ((threadIdx.x & 63) == 0) part[threadIdx.x >> 6] = ss;
    __syncthreads();
    if (threadIdx.x == 0) {
        float s = part[0] + part[1] + part[2] + part[3];
        dst[r] = 1.0f / fmaxf(sqrtf(s), EPSN);
    }
}

// ---------------------------------------------------------------------------
// Kernel 2: fp32 tiled GEMM with fused running max/argmax over the C axis.
// Grid: (B/BM) x CSPLIT. 256 threads, each computes an 8x8 register tile.
// LDS layout: XOR-swizzled 16B granules: row r, k-granule q stored at
// granule r*9 + (q ^ ((r>>3)&7)). This makes BOTH the staging writes and the
// 8-rows-per-thread b128 reads bank-conflict-free (plain padded row-major has
// a 16-way conflict because the per-lane row step of 8 rows x 36 floats is
// 0 mod 32 banks).
// Normalization is folded into the epilogue: sim = acc * inv_a[r] * inv_b[c].
// ---------------------------------------------------------------------------
__global__ __launch_bounds__(256, 1) void simmax_kernel(
    const float* __restrict__ A, const float* __restrict__ Bc,
    const float* __restrict__ inv_a, const float* __restrict__ inv_b,
    float* __restrict__ pmax, int* __restrict__ pidx)
{
    __shared__ float As[BM * 36];  // 128 rows x 9 granules x 4 floats
    __shared__ float Bs[BN * 36];

    const int tid  = threadIdx.x;
    const int tx   = tid & 15;   // column group (8 cols each)
    const int ty   = tid >> 4;   // row group (8 rows each)
    const int row0 = blockIdx.x * BM;
    const int c0   = blockIdx.y * CPER;

    float sa[8];
    #pragma unroll
    for (int i = 0; i < 8; ++i) sa[i] = inv_a[row0 + ty * 8 + i];

    float rmax[8];
    int   ridx[8];
    #pragma unroll
    for (int i = 0; i < 8; ++i) { rmax[i] = -1e30f; ridx[i] = 0; }

    for (int nc = 0; nc < CPER / BN; ++nc) {
        const int cbase = c0 + nc * BN;

        float acc[8][8];
        #pragma unroll
        for (int i = 0; i < 8; ++i)
            #pragma unroll
            for (int j = 0; j < 8; ++j) acc[i][j] = 0.0f;

        for (int kc = 0; kc < D_DIM / BK; ++kc) {
            const int kbase = kc * BK;
            __syncthreads();
            // stage A-tile [BM x BK] and B-tile [BN x BK]; raw copy, coalesced
            #pragma unroll
            for (int it = 0; it < 4; ++it) {
                int f  = it * 256 + tid;   // 0..1023 float4 slots
                int c  = f >> 3;           // tile row 0..127
                int kq = f & 7;            // k-granule 0..7
                int pg = c * 9 + (kq ^ ((c >> 3) & 7));
                float4 av = *(const float4*)(A  + (size_t)(row0 + c) * D_DIM + kbase + kq * 4);
                *(float4*)(As + pg * 4) = av;
                float4 bv = *(const float4*)(Bc + (size_t)(cbase + c) * D_DIM + kbase + kq * 4);
                *(float4*)(Bs + pg * 4) = bv;
            }
            __syncthreads();

            #pragma unroll
            for (int k4 = 0; k4 < 8; ++k4) {
                float4 a[8], b[8];
                #pragma unroll
                for (int i = 0; i < 8; ++i)
                    a[i] = *(const float4*)(As + (((ty * 8 + i) * 9) + (k4 ^ (ty & 7))) * 4);
                #pragma unroll
                for (int j = 0; j < 8; ++j)
                    b[j] = *(const float4*)(Bs + (((tx * 8 + j) * 9) + (k4 ^ (tx & 7))) * 4);
                #pragma unroll
                for (int i = 0; i < 8; ++i)
                    #pragma unroll
                    for (int j = 0; j < 8; ++j)
                        acc[i][j] += a[i].x * b[j].x + a[i].y * b[j].y
                                   + a[i].z * b[j].z + a[i].w * b[j].w;
            }
        }

        // epilogue for this n-chunk: scale by norms, update running argmax.
        // j ascending (and nc ascending) + strict '>' == first-occurrence ties.
        #pragma unroll
        for (int j = 0; j < 8; ++j) {
            const int   cg = cbase + tx * 8 + j;
            const float sb = inv_b[cg];
            #pragma unroll
            for (int i = 0; i < 8; ++i) {
                float v = acc[i][j] * sa[i] * sb;
                if (v > rmax[i]) { rmax[i] = v; ridx[i] = cg; }
            }
        }
    }

    // cross-lane reduction over the 16 tx lanes of each ty (contiguous lanes)
    #pragma unroll
    for (int i = 0; i < 8; ++i) {
        float v  = rmax[i];
        int   ix = ridx[i];
        #pragma unroll
        for (int off = 8; off; off >>= 1) {
            float ov = __shfl_down(v,  off, 64);
            int   oi = __shfl_down(ix, off, 64);
            if (ov > v || (ov == v && oi < ix)) { v = ov; ix = oi; }
        }
        if (tx == 0) {
            int out_i = blockIdx.y * B_ROWS + row0 + ty * 8 + i;
            pmax[out_i] = v;
            pidx[out_i] = ix;
        }
    }
}

// ---------------------------------------------------------------------------
// Kernel 3: combine CSPLIT partials, apply clip semantics, write outputs.
// d_out[0..B) = novelty (float), d_out[B..2B) = closest (written as float).
// ---------------------------------------------------------------------------
__global__ __launch_bounds__(256) void finalize_kernel(
    const float* __restrict__ pmax, const int* __restrict__ pidx,
    float* __restrict__ out)
{
    int i = blockIdx.x * blockDim.x + threadIdx.x;
    if (i >= B_ROWS) return;
    float m = -1e30f; int ix = 0;
    #pragma unroll
    for (int s = 0; s < CSPLIT; ++s) {
        float v  = pmax[s * B_ROWS + i];
        int   id = pidx[s * B_ROWS + i];
        if (v > m || (v == m && id < ix)) { m = v; ix = id; }
    }
    // Reference clips sims to [0,1] BEFORE argmax: if every sim <= 0 they all
    // clip to 0 and argmax returns index 0.
    if (m <= 0.0f) ix = 0;
    float ms  = fminf(fmaxf(m, 0.0f), 1.0f);
    float nov = fminf(fmaxf(sqrtf(1.0f - ms), 0.0f), 1.0f);
    out[i]          = nov;
    out[B_ROWS + i] = (float)ix;
}

// ---------------------------------------------------------------------------
// Workspace layout (floats):
//   [0, 8192)                    inv_emb
//   [8192, 8192+4096)            inv_cen
//   [12288, 12288+4*8192)        pmax  (CSPLIT x B)
//   then 4*8192 ints             pidx
// Total ~304 KB.
// ---------------------------------------------------------------------------
extern "C" void kernel_launch(void* const* d_in, const int* in_sizes, int n_in,
                              void* d_out, int out_size, void* d_ws, size_t ws_size,
                              hipStream_t stream)
{
    const float* emb = (const float*)d_in[0];
    const float* cen = (const float*)d_in[1];
    float* out = (float*)d_out;

    float* inv_emb = (float*)d_ws;
    float* inv_cen = inv_emb + B_ROWS;
    float* pmax    = inv_cen + C_COLS;
    int*   pidx    = (int*)(pmax + CSPLIT * B_ROWS);

    norms_kernel<<<B_ROWS + C_COLS, 256, 0, stream>>>(emb, cen, inv_emb, inv_cen);

    dim3 grid(B_ROWS / BM, CSPLIT);
    simmax_kernel<<<grid, 256, 0, stream>>>(emb, cen, inv_emb, inv_cen, pmax, pidx);

    finalize_kernel<<<(B_ROWS + 255) / 256, 256, 0, stream>>>(pmax, pidx, out);
}

// Round 2
// 379.898 us; speedup vs baseline: 33.1995x; 33.1995x over previous
//
#include <hip/hip_runtime.h>
#include <math.h>

#define B_ROWS 8192
#define C_COLS 4096
#define D_DIM  1024
#define EPSN   1e-12f

typedef float v4f __attribute__((ext_vector_type(4)));
typedef short v8s __attribute__((ext_vector_type(8)));

__device__ __forceinline__ unsigned short bf16_rtn(float x) {
    unsigned int u = __float_as_uint(x);
    u += 0x7fffu + ((u >> 16) & 1u);
    return (unsigned short)(u >> 16);
}
__device__ __forceinline__ float bf16_to_f(unsigned short h) {
    return __uint_as_float(((unsigned int)h) << 16);
}

// better(): total order (value desc, index asc) -- matches first-occurrence argmax
__device__ __forceinline__ bool better_vi(float v, int i, float V, int I) {
    return (v > V) || (v == V && i < I);
}
// merge sorted pair (b1>=b2) into sorted pair (a1>=a2), keeping global top-2
__device__ __forceinline__ void top2_merge(float& a1v, int& a1i, float& a2v, int& a2i,
                                           float b1v, int b1i, float b2v, int b2i) {
    if (better_vi(b1v, b1i, a1v, a1i)) {
        if (better_vi(a1v, a1i, b2v, b2i)) { a2v = a1v; a2i = a1i; }
        else                               { a2v = b2v; a2i = b2i; }
        a1v = b1v; a1i = b1i;
    } else if (better_vi(b1v, b1i, a2v, a2i)) {
        a2v = b1v; a2i = b1i;
    }
}

// ---------------------------------------------------------------------------
// Kernel 1: normalize rows in fp32, split into bf16 hi + bf16 lo residual.
// One block per row (A rows first, then B rows). Also stores 1/||x|| for the
// fp32 rescore pass.
// ---------------------------------------------------------------------------
__global__ __launch_bounds__(256) void prep_kernel(
    const float* __restrict__ emb, const float* __restrict__ cen,
    unsigned short* __restrict__ Ah, unsigned short* __restrict__ Al,
    unsigned short* __restrict__ Bh, unsigned short* __restrict__ Bl,
    float* __restrict__ inv_a, float* __restrict__ inv_b)
{
    int row = blockIdx.x;
    const float* src; unsigned short *hi, *lo; float* invp; int r;
    if (row < B_ROWS) { src = emb; r = row;          hi = Ah; lo = Al; invp = inv_a; }
    else              { src = cen; r = row - B_ROWS; hi = Bh; lo = Bl; invp = inv_b; }

    const float4 v = *(const float4*)(src + (size_t)r * D_DIM + threadIdx.x * 4);
    float ss = v.x * v.x + v.y * v.y + v.z * v.z + v.w * v.w;
    #pragma unroll
    for (int off = 32; off; off >>= 1) ss += __shfl_down(ss, off, 64);

    __shared__ float part[4];
    __shared__ float sinv;
    if ((threadIdx.x & 63) == 0) part[threadIdx.x >> 6] = ss;
    __syncthreads();
    if (threadIdx.x == 0) {
        float s  = part[0] + part[1] + part[2] + part[3];
        float iv = 1.0f / fmaxf(sqrtf(s), EPSN);
        invp[r] = iv;
        sinv    = iv;
    }
    __syncthreads();
    const float iv = sinv;

    float xs[4] = { v.x * iv, v.y * iv, v.z * iv, v.w * iv };
    ushort4 H, L;
    unsigned short h;
    h = bf16_rtn(xs[0]); H.x = h; L.x = bf16_rtn(xs[0] - bf16_to_f(h));
    h = bf16_rtn(xs[1]); H.y = h; L.y = bf16_rtn(xs[1] - bf16_to_f(h));
    h = bf16_rtn(xs[2]); H.z = h; L.z = bf16_rtn(xs[2] - bf16_to_f(h));
    h = bf16_rtn(xs[3]); H.w = h; L.w = bf16_rtn(xs[3] - bf16_to_f(h));
    *(ushort4*)(hi + (size_t)r * D_DIM + threadIdx.x * 4) = H;
    *(ushort4*)(lo + (size_t)r * D_DIM + threadIdx.x * 4) = L;
}

// ---------------------------------------------------------------------------
// Kernel 2: split-bf16 MFMA GEMM (3 terms) + fused per-row top-2 over cols.
// Grid 64x32, 256 threads = 4 waves in 2x2; wave does 64x64 via 4x4 MFMAs of
// 16x16x32. BK=32. Staging: global_load_lds width=16 into 4 LDS tiles
// (Ah/Al/Bh/Bl, 128x32 bf16 each, 32 KB total). 16B chunks are XOR-swizzled
// (phys = row*4 + (q ^ ((row>>1)&3))) so fragment ds_read_b128 is 2-way max
// (free). Inputs are pre-normalized so acc IS the cosine sim.
// ---------------------------------------------------------------------------
__global__ __launch_bounds__(256, 2) void simmax_kernel(
    const unsigned short* __restrict__ Ahg, const unsigned short* __restrict__ Alg,
    const unsigned short* __restrict__ Bhg, const unsigned short* __restrict__ Blg,
    float* __restrict__ p1v, int* __restrict__ p1i,
    float* __restrict__ p2v, int* __restrict__ p2i)
{
    __shared__ unsigned short lds[4 * 4096];  // AH | AL | BH | BL, 4096 shorts each

    const int tid    = threadIdx.x;
    const int L      = tid & 63;
    const int w      = tid >> 6;
    const int lane15 = L & 15;
    const int quad   = L >> 4;
    const int wr     = w >> 1, wc = w & 1;
    const int row0   = blockIdx.x * 128;
    const int c0     = blockIdx.y * 128;

    // staging geometry: 512 chunks/tile, 2 issues/thread, lane-contiguous LDS
    int srow[2], sgq[2];
    #pragma unroll
    for (int i = 0; i < 2; ++i) {
        int p   = i * 256 + tid;
        int rr  = p >> 2;
        srow[i] = rr;
        sgq[i]  = (p & 3) ^ ((rr >> 1) & 3);
    }
    size_t oA[2], oB[2];
    #pragma unroll
    for (int i = 0; i < 2; ++i) {
        oA[i] = (size_t)(row0 + srow[i]) * D_DIM + sgq[i] * 8;
        oB[i] = (size_t)(c0   + srow[i]) * D_DIM + sgq[i] * 8;
    }
    const int lb[2] = { (0 * 256 + w * 64) * 8, (1 * 256 + w * 64) * 8 };  // shorts

    v4f acc[4][4];
    #pragma unroll
    for (int mt = 0; mt < 4; ++mt)
        #pragma unroll
        for (int nt = 0; nt < 4; ++nt) acc[mt][nt] = (v4f)0.0f;

    // precompute fragment LDS chunk offsets (shorts)
    int fA[4], fB[4];
    #pragma unroll
    for (int mt = 0; mt < 4; ++mt) {
        int rA = wr * 64 + mt * 16 + lane15;
        fA[mt] = (rA * 4 + (quad ^ ((rA >> 1) & 3))) * 8;
        int rB = wc * 64 + mt * 16 + lane15;
        fB[mt] = (rB * 4 + (quad ^ ((rB >> 1) & 3))) * 8;
    }

    for (int kc = 0; kc < D_DIM / 32; ++kc) {
        const int kb = kc * 32;
        #pragma unroll
        for (int i = 0; i < 2; ++i) {
            __builtin_amdgcn_global_load_lds(
                (const __attribute__((address_space(1))) void*)(Ahg + oA[i] + kb),
                (__attribute__((address_space(3))) void*)&lds[0 + lb[i]], 16, 0, 0);
            __builtin_amdgcn_global_load_lds(
                (const __attribute__((address_space(1))) void*)(Alg + oA[i] + kb),
                (__attribute__((address_space(3))) void*)&lds[4096 + lb[i]], 16, 0, 0);
            __builtin_amdgcn_global_load_lds(
                (const __attribute__((address_space(1))) void*)(Bhg + oB[i] + kb),
                (__attribute__((address_space(3))) void*)&lds[8192 + lb[i]], 16, 0, 0);
            __builtin_amdgcn_global_load_lds(
                (const __attribute__((address_space(1))) void*)(Blg + oB[i] + kb),
                (__attribute__((address_space(3))) void*)&lds[12288 + lb[i]], 16, 0, 0);
        }
        __syncthreads();

        v8s fah[4], fal[4], fbh[4], fbl[4];
        #pragma unroll
        for (int t = 0; t < 4; ++t) {
            fah[t] = *(const v8s*)&lds[0     + fA[t]];
            fal[t] = *(const v8s*)&lds[4096  + fA[t]];
            fbh[t] = *(const v8s*)&lds[8192  + fB[t]];
            fbl[t] = *(const v8s*)&lds[12288 + fB[t]];
        }
        #pragma unroll
        for (int mt = 0; mt < 4; ++mt)
            #pragma unroll
            for (int nt = 0; nt < 4; ++nt) {
                acc[mt][nt] = __builtin_amdgcn_mfma_f32_16x16x32_bf16(fah[mt], fbh[nt], acc[mt][nt], 0, 0, 0);
                acc[mt][nt] = __builtin_amdgcn_mfma_f32_16x16x32_bf16(fah[mt], fbl[nt], acc[mt][nt], 0, 0, 0);
                acc[mt][nt] = __builtin_amdgcn_mfma_f32_16x16x32_bf16(fal[mt], fbh[nt], acc[mt][nt], 0, 0, 0);
            }
        __syncthreads();
    }

    // fused top-2 epilogue. C/D layout: col = lane&15, row = quad*4 + reg.
    const int pc = blockIdx.y * 2 + wc;
    #pragma unroll
    for (int mt = 0; mt < 4; ++mt) {
        #pragma unroll
        for (int r = 0; r < 4; ++r) {
            float a1v = acc[mt][0][r];
            int   a1i = c0 + wc * 64 + 0 * 16 + lane15;
            float a2v = -1e30f;
            int   a2i = 0x7fffffff;
            #pragma unroll
            for (int nt = 1; nt < 4; ++nt) {
                float v  = acc[mt][nt][r];
                int   ci = c0 + wc * 64 + nt * 16 + lane15;
                if (better_vi(v, ci, a1v, a1i))      { a2v = a1v; a2i = a1i; a1v = v; a1i = ci; }
                else if (better_vi(v, ci, a2v, a2i)) { a2v = v;   a2i = ci; }
            }
            #pragma unroll
            for (int off = 1; off < 16; off <<= 1) {
                float b1v = __shfl_xor(a1v, off, 64); int b1i = __shfl_xor(a1i, off, 64);
                float b2v = __shfl_xor(a2v, off, 64); int b2i = __shfl_xor(a2i, off, 64);
                top2_merge(a1v, a1i, a2v, a2i, b1v, b1i, b2v, b2i);
            }
            if (lane15 == 0) {
                int rg = blockIdx.x * 128 + wr * 64 + mt * 16 + quad * 4 + r;
                size_t ix = (size_t)pc * B_ROWS + rg;
                p1v[ix] = a1v; p1i[ix] = a1i;
                p2v[ix] = a2v; p2i[ix] = a2i;
            }
        }
    }
}

// ---------------------------------------------------------------------------
// Kernel 3: merge 64 partial top-2 sets per row, rescore both candidates in
// exact fp32 (dot * inv_a * inv_b -- identical semantics to the round-1
// passing kernel), apply clip/argmax edge cases, write outputs.
// One wave per row; 4 rows per block.
// ---------------------------------------------------------------------------
__global__ __launch_bounds__(256) void finalize_kernel(
    const float* __restrict__ emb, const float* __restrict__ cen,
    const float* __restrict__ inv_a, const float* __restrict__ inv_b,
    const float* __restrict__ p1v, const int* __restrict__ p1i,
    const float* __restrict__ p2v, const int* __restrict__ p2i,
    float* __restrict__ out)
{
    const int lane = threadIdx.x & 63;
    const int row  = blockIdx.x * 4 + (threadIdx.x >> 6);

    size_t ix = (size_t)lane * B_ROWS + row;
    float a1v = p1v[ix]; int a1i = p1i[ix];
    float a2v = p2v[ix]; int a2i = p2i[ix];
    #pragma unroll
    for (int off = 1; off < 64; off <<= 1) {
        float b1v = __shfl_xor(a1v, off, 64); int b1i = __shfl_xor(a1i, off, 64);
        float b2v = __shfl_xor(a2v, off, 64); int b2i = __shfl_xor(a2i, off, 64);
        top2_merge(a1v, a1i, a2v, a2i, b1v, b1i, b2v, b2i);
    }
    const int i1 = a1i, i2 = a2i;

    // fp32 rescore of both candidates
    const float* er = emb + (size_t)row * D_DIM;
    const float* c1 = cen + (size_t)i1 * D_DIM;
    const float* c2 = cen + (size_t)i2 * D_DIM;
    float d1 = 0.0f, d2 = 0.0f;
    #pragma unroll
    for (int j = 0; j < 4; ++j) {
        int e = (j * 64 + lane) * 4;
        float4 ev = *(const float4*)(er + e);
        float4 x1 = *(const float4*)(c1 + e);
        float4 x2 = *(const float4*)(c2 + e);
        d1 += ev.x * x1.x + ev.y * x1.y + ev.z * x1.z + ev.w * x1.w;
        d2 += ev.x * x2.x + ev.y * x2.y + ev.z * x2.z + ev.w * x2.w;
    }
    #pragma unroll
    for (int off = 1; off < 64; off <<= 1) {
        d1 += __shfl_xor(d1, off, 64);
        d2 += __shfl_xor(d2, off, 64);
    }

    if (lane == 0) {
        float ia = inv_a[row];
        float s1 = d1 * ia * inv_b[i1];
        float s2 = d2 * ia * inv_b[i2];
        float m; int ci;
        if (better_vi(s2, i2, s1, i1)) { m = s2; ci = i2; }
        else                           { m = s1; ci = i1; }
        if (m <= 0.0f) ci = 0;  // all sims clip to 0 -> argmax = 0
        float ms  = fminf(fmaxf(m, 0.0f), 1.0f);
        out[row]          = fminf(fmaxf(sqrtf(1.0f - ms), 0.0f), 1.0f);
        out[B_ROWS + row] = (float)ci;
    }
}

// ---------------------------------------------------------------------------
// Workspace layout (~57 MB):
//   Ah 16MB | Al 16MB | Bh 8MB | Bl 8MB | inv_a 32KB | inv_b 16KB |
//   p1v 2MB | p1i 2MB | p2v 2MB | p2i 2MB
// ---------------------------------------------------------------------------
extern "C" void kernel_launch(void* const* d_in, const int* in_sizes, int n_in,
                              void* d_out, int out_size, void* d_ws, size_t ws_size,
                              hipStream_t stream)
{
    const float* emb = (const float*)d_in[0];
    const float* cen = (const float*)d_in[1];
    float* out = (float*)d_out;

    unsigned short* Ahp = (unsigned short*)d_ws;
    unsigned short* Alp = Ahp + (size_t)B_ROWS * D_DIM;
    unsigned short* Bhp = Alp + (size_t)B_ROWS * D_DIM;
    unsigned short* Blp = Bhp + (size_t)C_COLS * D_DIM;
    float* inv_a = (float*)(Blp + (size_t)C_COLS * D_DIM);
    float* inv_b = inv_a + B_ROWS;
    float* p1v   = inv_b + C_COLS;
    int*   p1i   = (int*)(p1v + 64 * B_ROWS);
    float* p2v   = (float*)(p1i + 64 * B_ROWS);
    int*   p2i   = (int*)(p2v + 64 * B_ROWS);

    prep_kernel<<<B_ROWS + C_COLS, 256, 0, stream>>>(emb, cen, Ahp, Alp, Bhp, Blp, inv_a, inv_b);

    dim3 grid(B_ROWS / 128, C_COLS / 128);
    simmax_kernel<<<grid, 256, 0, stream>>>(Ahp, Alp, Bhp, Blp, p1v, p1i, p2v, p2i);

    finalize_kernel<<<B_ROWS / 4, 256, 0, stream>>>(emb, cen, inv_a, inv_b,
                                                    p1v, p1i, p2v, p2i, out);
}

// Round 3
// 213.890 us; speedup vs baseline: 58.9670x; 1.7761x over previous
//
#include <hip/hip_runtime.h>
#include <math.h>

#define B_ROWS 8192
#define C_COLS 4096
#define D_DIM  1024
#define EPSN   1e-12f

typedef float v4f __attribute__((ext_vector_type(4)));
typedef short v8s __attribute__((ext_vector_type(8)));

__device__ __forceinline__ unsigned short bf16_rtn(float x) {
    unsigned int u = __float_as_uint(x);
    u += 0x7fffu + ((u >> 16) & 1u);
    return (unsigned short)(u >> 16);
}

// strict total order (value desc, index asc) == first-occurrence argmax
__device__ __forceinline__ bool better_vi(float v, int i, float V, int I) {
    return (v > V) || (v == V && i < I);
}

// ---------------------------------------------------------------------------
// Kernel 1: wave-per-row normalize + bf16 convert. No LDS, no barriers.
// Lane j holds floats (j, j+64, j+128, j+192)*4; butterfly-sum the squares.
// ---------------------------------------------------------------------------
__global__ __launch_bounds__(256) void prep_kernel(
    const float* __restrict__ emb, const float* __restrict__ cen,
    unsigned short* __restrict__ Ah, unsigned short* __restrict__ Bh,
    float* __restrict__ inv_a, float* __restrict__ inv_b)
{
    const int lane = threadIdx.x & 63;
    const int wid  = blockIdx.x * 4 + (threadIdx.x >> 6);
    const float* src; unsigned short* dst; float* invp; int r;
    if (wid < B_ROWS) { src = emb; r = wid;          dst = Ah; invp = inv_a; }
    else              { src = cen; r = wid - B_ROWS; dst = Bh; invp = inv_b; }

    const float* rp = src + (size_t)r * D_DIM;
    float4 v[4];
    float ss = 0.0f;
    #pragma unroll
    for (int j = 0; j < 4; ++j) {
        v[j] = *(const float4*)(rp + (j * 64 + lane) * 4);
        ss += v[j].x * v[j].x + v[j].y * v[j].y + v[j].z * v[j].z + v[j].w * v[j].w;
    }
    #pragma unroll
    for (int off = 1; off < 64; off <<= 1) ss += __shfl_xor(ss, off, 64);

    const float iv = 1.0f / fmaxf(sqrtf(ss), EPSN);
    if (lane == 0) invp[r] = iv;

    unsigned short* dp = dst + (size_t)r * D_DIM;
    #pragma unroll
    for (int j = 0; j < 4; ++j) {
        ushort4 H;
        H.x = bf16_rtn(v[j].x * iv);
        H.y = bf16_rtn(v[j].y * iv);
        H.z = bf16_rtn(v[j].z * iv);
        H.w = bf16_rtn(v[j].w * iv);
        *(ushort4*)(dp + (j * 64 + lane) * 4) = H;
    }
}

// ---------------------------------------------------------------------------
// Kernel 2: single-term bf16 MFMA GEMM + fused per-row top-2 over cols.
// m97 structure: 128x128 tile, BK=32, 4 waves (2x2), wave = 4x4 MFMAs of
// 16x16x32. global_load_lds width=16 into 2 LDS tiles (16 KB). 16B chunks
// XOR-swizzled (phys = row*4 + (q ^ ((row>>1)&3))): staging writes AND
// fragment ds_read_b128 both conflict-free (verified 0 conflicts in R2).
// Inputs pre-normalized => acc IS the cosine sim. Partials stored [row][pc]
// for coalesced finalize gather.
// ---------------------------------------------------------------------------
__global__ __launch_bounds__(256, 4) void simmax_kernel(
    const unsigned short* __restrict__ Ahg, const unsigned short* __restrict__ Bhg,
    float* __restrict__ p1v, int* __restrict__ p1i,
    float* __restrict__ p2v, int* __restrict__ p2i)
{
    __shared__ unsigned short lds[2 * 4096];  // A | B tiles, 4096 shorts each

    const int tid    = threadIdx.x;
    const int L      = tid & 63;
    const int w      = tid >> 6;
    const int lane15 = L & 15;
    const int quad   = L >> 4;
    const int wr     = w >> 1, wc = w & 1;
    const int row0   = blockIdx.x * 128;
    const int c0     = blockIdx.y * 128;

    // staging: 512 chunks/tile, 2 issues/thread/tile, lane-contiguous LDS dest
    int srow[2], sgq[2];
    #pragma unroll
    for (int i = 0; i < 2; ++i) {
        int p   = i * 256 + tid;
        int rr  = p >> 2;
        srow[i] = rr;
        sgq[i]  = (p & 3) ^ ((rr >> 1) & 3);
    }
    size_t oA[2], oB[2];
    #pragma unroll
    for (int i = 0; i < 2; ++i) {
        oA[i] = (size_t)(row0 + srow[i]) * D_DIM + sgq[i] * 8;
        oB[i] = (size_t)(c0   + srow[i]) * D_DIM + sgq[i] * 8;
    }
    const int lb[2] = { (0 * 256 + w * 64) * 8, (1 * 256 + w * 64) * 8 };  // shorts

    v4f acc[4][4];
    #pragma unroll
    for (int mt = 0; mt < 4; ++mt)
        #pragma unroll
        for (int nt = 0; nt < 4; ++nt) acc[mt][nt] = (v4f)0.0f;

    int fA[4], fB[4];
    #pragma unroll
    for (int t = 0; t < 4; ++t) {
        int rA = wr * 64 + t * 16 + lane15;
        fA[t] = (rA * 4 + (quad ^ ((rA >> 1) & 3))) * 8;
        int rB = wc * 64 + t * 16 + lane15;
        fB[t] = (rB * 4 + (quad ^ ((rB >> 1) & 3))) * 8;
    }

    for (int kc = 0; kc < D_DIM / 32; ++kc) {
        const int kb = kc * 32;
        #pragma unroll
        for (int i = 0; i < 2; ++i) {
            __builtin_amdgcn_global_load_lds(
                (const __attribute__((address_space(1))) void*)(Ahg + oA[i] + kb),
                (__attribute__((address_space(3))) void*)&lds[0 + lb[i]], 16, 0, 0);
            __builtin_amdgcn_global_load_lds(
                (const __attribute__((address_space(1))) void*)(Bhg + oB[i] + kb),
                (__attribute__((address_space(3))) void*)&lds[4096 + lb[i]], 16, 0, 0);
        }
        __syncthreads();

        v8s fah[4], fbh[4];
        #pragma unroll
        for (int t = 0; t < 4; ++t) {
            fah[t] = *(const v8s*)&lds[0    + fA[t]];
            fbh[t] = *(const v8s*)&lds[4096 + fB[t]];
        }
        #pragma unroll
        for (int mt = 0; mt < 4; ++mt)
            #pragma unroll
            for (int nt = 0; nt < 4; ++nt)
                acc[mt][nt] = __builtin_amdgcn_mfma_f32_16x16x32_bf16(fah[mt], fbh[nt], acc[mt][nt], 0, 0, 0);
        __syncthreads();
    }

    // fused top-2 epilogue. C/D layout: col = lane&15, row = quad*4 + reg.
    const int pc = blockIdx.y * 2 + wc;  // 0..63 column chunk id
    #pragma unroll
    for (int mt = 0; mt < 4; ++mt) {
        #pragma unroll
        for (int r = 0; r < 4; ++r) {
            float a1v = acc[mt][0][r];
            int   a1i = c0 + wc * 64 + 0 * 16 + lane15;
            float a2v = -1e30f;
            int   a2i = 0x7fffffff;
            #pragma unroll
            for (int nt = 1; nt < 4; ++nt) {
                float v  = acc[mt][nt][r];
                int   ci = c0 + wc * 64 + nt * 16 + lane15;
                if (better_vi(v, ci, a1v, a1i))      { a2v = a1v; a2i = a1i; a1v = v; a1i = ci; }
                else if (better_vi(v, ci, a2v, a2i)) { a2v = v;   a2i = ci; }
            }
            // down-sweep over the 16 cols of this quad group (lane0 of group valid)
            #pragma unroll
            for (int off = 8; off; off >>= 1) {
                float b1v = __shfl_down(a1v, off, 64); int b1i = __shfl_down(a1i, off, 64);
                float b2v = __shfl_down(a2v, off, 64); int b2i = __shfl_down(a2i, off, 64);
                // merge sorted pairs keeping top-2
                if (better_vi(b1v, b1i, a1v, a1i)) {
                    if (better_vi(a1v, a1i, b2v, b2i)) { a2v = a1v; a2i = a1i; }
                    else                               { a2v = b2v; a2i = b2i; }
                    a1v = b1v; a1i = b1i;
                } else if (better_vi(b1v, b1i, a2v, a2i)) {
                    a2v = b1v; a2i = b1i;
                }
            }
            if (lane15 == 0) {
                int rg = row0 + wr * 64 + mt * 16 + quad * 4 + r;
                size_t ix = (size_t)rg * 64 + pc;  // [row][chunk] layout
                p1v[ix] = a1v; p1i[ix] = a1i;
                p2v[ix] = a2v; p2i[ix] = a2i;
            }
        }
    }
}

// ---------------------------------------------------------------------------
// Kernel 3: wave per row. Coalesced gather of 64 top-2 partials, butterfly
// merge into global top-4, rescore all 4 candidates in exact fp32, pick with
// first-occurrence semantics, apply clip edge cases, write outputs.
// ---------------------------------------------------------------------------
__global__ __launch_bounds__(256) void finalize_kernel(
    const float* __restrict__ emb, const float* __restrict__ cen,
    const float* __restrict__ inv_a, const float* __restrict__ inv_b,
    const float* __restrict__ p1v, const int* __restrict__ p1i,
    const float* __restrict__ p2v, const int* __restrict__ p2i,
    float* __restrict__ out)
{
    const int lane = threadIdx.x & 63;
    const int row  = blockIdx.x * 4 + (threadIdx.x >> 6);
    const size_t base = (size_t)row * 64 + lane;

    // per-lane sorted-4 list (2 real + 2 sentinels)
    float v[4]; int ix[4];
    v[0] = p1v[base]; ix[0] = p1i[base];
    v[1] = p2v[base]; ix[1] = p2i[base];
    v[2] = -1e30f;    ix[2] = 0x7ffffffe;
    v[3] = -1e30f;    ix[3] = 0x7fffffff;

    // butterfly: each step merges disjoint candidate sets; all lanes converge
    #pragma unroll
    for (int off = 1; off < 64; off <<= 1) {
        float ov[4]; int oi[4];
        #pragma unroll
        for (int k = 0; k < 4; ++k) {
            ov[k] = __shfl_xor(v[k],  off, 64);
            oi[k] = __shfl_xor(ix[k], off, 64);
        }
        #pragma unroll
        for (int k = 0; k < 4; ++k) {
            float bv = ov[k]; int bi = oi[k];
            bool b0 = better_vi(bv, bi, v[0], ix[0]);
            bool b1 = better_vi(bv, bi, v[1], ix[1]);
            bool b2 = better_vi(bv, bi, v[2], ix[2]);
            bool b3 = better_vi(bv, bi, v[3], ix[3]);
            float nv3 = b2 ? v[2] : (b3 ? bv : v[3]); int ni3 = b2 ? ix[2] : (b3 ? bi : ix[3]);
            float nv2 = b1 ? v[1] : (b2 ? bv : v[2]); int ni2 = b1 ? ix[1] : (b2 ? bi : ix[2]);
            float nv1 = b0 ? v[0] : (b1 ? bv : v[1]); int ni1 = b0 ? ix[0] : (b1 ? bi : ix[1]);
            float nv0 = b0 ? bv   : v[0];             int ni0 = b0 ? bi    : ix[0];
            v[0] = nv0; ix[0] = ni0; v[1] = nv1; ix[1] = ni1;
            v[2] = nv2; ix[2] = ni2; v[3] = nv3; ix[3] = ni3;
        }
    }
    // 128 real candidates per row => all 4 slots hold real (distinct) indices

    // exact fp32 rescore of the 4 candidates (whole wave cooperates)
    const float* er = emb + (size_t)row * D_DIM;
    float4 ev[4];
    #pragma unroll
    for (int j = 0; j < 4; ++j) ev[j] = *(const float4*)(er + (j * 64 + lane) * 4);

    float d[4];
    #pragma unroll
    for (int c = 0; c < 4; ++c) {
        const float* cr = cen + (size_t)ix[c] * D_DIM;
        float s = 0.0f;
        #pragma unroll
        for (int j = 0; j < 4; ++j) {
            float4 cv = *(const float4*)(cr + (j * 64 + lane) * 4);
            s += ev[j].x * cv.x + ev[j].y * cv.y + ev[j].z * cv.z + ev[j].w * cv.w;
        }
        d[c] = s;
    }
    #pragma unroll
    for (int off = 1; off < 64; off <<= 1) {
        #pragma unroll
        for (int c = 0; c < 4; ++c) d[c] += __shfl_xor(d[c], off, 64);
    }

    if (lane == 0) {
        const float ia = inv_a[row];
        float m = -1e30f; int ci = 0x7fffffff;
        #pragma unroll
        for (int c = 0; c < 4; ++c) {
            float s = d[c] * ia * inv_b[ix[c]];
            if (better_vi(s, ix[c], m, ci)) { m = s; ci = ix[c]; }
        }
        if (m <= 0.0f) ci = 0;  // all sims clip to 0 -> argmax = 0
        float ms = fminf(fmaxf(m, 0.0f), 1.0f);
        out[row]          = fminf(fmaxf(sqrtf(1.0f - ms), 0.0f), 1.0f);
        out[B_ROWS + row] = (float)ci;
    }
}

// ---------------------------------------------------------------------------
// Workspace (~33 MB): Ah 16MB | Bh 8MB | inv_a 32KB | inv_b 16KB |
//                     p1v/p1i/p2v/p2i 2MB each ([row][chunk] layout)
// ---------------------------------------------------------------------------
extern "C" void kernel_launch(void* const* d_in, const int* in_sizes, int n_in,
                              void* d_out, int out_size, void* d_ws, size_t ws_size,
                              hipStream_t stream)
{
    const float* emb = (const float*)d_in[0];
    const float* cen = (const float*)d_in[1];
    float* out = (float*)d_out;

    unsigned short* Ahp = (unsigned short*)d_ws;
    unsigned short* Bhp = Ahp + (size_t)B_ROWS * D_DIM;
    float* inv_a = (float*)(Bhp + (size_t)C_COLS * D_DIM);
    float* inv_b = inv_a + B_ROWS;
    float* p1v   = inv_b + C_COLS;
    int*   p1i   = (int*)(p1v + (size_t)64 * B_ROWS);
    float* p2v   = (float*)(p1i + (size_t)64 * B_ROWS);
    int*   p2i   = (int*)(p2v + (size_t)64 * B_ROWS);

    prep_kernel<<<(B_ROWS + C_COLS) / 4, 256, 0, stream>>>(emb, cen, Ahp, Bhp, inv_a, inv_b);

    dim3 grid(B_ROWS / 128, C_COLS / 128);
    simmax_kernel<<<grid, 256, 0, stream>>>(Ahp, Bhp, p1v, p1i, p2v, p2i);

    finalize_kernel<<<B_ROWS / 4, 256, 0, stream>>>(emb, cen, inv_a, inv_b,
                                                    p1v, p1i, p2v, p2i, out);
}